// Round 1
// baseline (652.139 us; speedup 1.0000x reference)
//
#include <hip/hip_runtime.h>

typedef __attribute__((ext_vector_type(8))) short bf16x8;
typedef __attribute__((ext_vector_type(4))) float f32x4;

#define MTOK 4096
#define HD 1024
#define FD 2048
#define NEXP 8
#define MAXT 72   // >= sum ceil(cnt_e/128) <= 64+7

struct Ctl {
  int counts[NEXP];
  int cursor[NEXP];
  int totalTiles;
  int _pad[7];
  int4 tileMap[MAXT];        // {expert, growStart, rowsValid, 0}
  int topE[MTOK][2];
  float topW[MTOK][2];
  int pos[MTOK][2];
  int rowTok[2 * MTOK];
};

__device__ __forceinline__ unsigned short f2bf(float f) {
  unsigned int u = __float_as_uint(f);
  unsigned int r = u + 0x7fffu + ((u >> 16) & 1u);   // RNE
  return (unsigned short)(r >> 16);
}
__device__ __forceinline__ float bf2f(unsigned short s) {
  return __uint_as_float(((unsigned int)s) << 16);
}
__device__ __forceinline__ unsigned int pk2(float a, float b) {
  return (unsigned int)f2bf(a) | ((unsigned int)f2bf(b) << 16);
}

// ---------------- router: logits -> top2 -> renorm weights -> counts ----------------
__global__ void k_router(const float* __restrict__ x, const float* __restrict__ gw,
                         Ctl* __restrict__ ctl) {
  int gt = blockIdx.x * blockDim.x + threadIdx.x;
  int tok = gt >> 6;
  int lane = gt & 63;
  if (tok >= MTOK) return;
  const float* xr = x + (size_t)tok * HD;
  float acc[NEXP];
#pragma unroll
  for (int e = 0; e < NEXP; e++) acc[e] = 0.f;
  for (int h = lane; h < HD; h += 64) {
    float xv = xr[h];
    float4 g0 = *(const float4*)(gw + h * NEXP);
    float4 g1 = *(const float4*)(gw + h * NEXP + 4);
    acc[0] += xv * g0.x; acc[1] += xv * g0.y; acc[2] += xv * g0.z; acc[3] += xv * g0.w;
    acc[4] += xv * g1.x; acc[5] += xv * g1.y; acc[6] += xv * g1.z; acc[7] += xv * g1.w;
  }
#pragma unroll
  for (int off = 32; off > 0; off >>= 1) {
#pragma unroll
    for (int e = 0; e < NEXP; e++) acc[e] += __shfl_xor(acc[e], off);
  }
  if (lane == 0) {
    float l0 = -1e30f, l1 = -1e30f; int i0 = 0, i1 = 0;
#pragma unroll
    for (int e = 0; e < NEXP; e++) {
      float v = acc[e];
      if (v > l0) { l1 = l0; i1 = i0; l0 = v; i0 = e; }
      else if (v > l1) { l1 = v; i1 = e; }
    }
    float w0 = 1.f / (1.f + __expf(l1 - l0));  // = e^l0/(e^l0+e^l1)
    ctl->topE[tok][0] = i0; ctl->topE[tok][1] = i1;
    ctl->topW[tok][0] = w0; ctl->topW[tok][1] = 1.f - w0;
    atomicAdd(&ctl->counts[i0], 1);
    atomicAdd(&ctl->counts[i1], 1);
  }
}

// ---------------- prefix sums + tile map ----------------
__global__ void k_setup(Ctl* __restrict__ ctl) {
  if (threadIdx.x == 0 && blockIdx.x == 0) {
    int off = 0, t = 0;
    for (int e = 0; e < NEXP; e++) {
      ctl->cursor[e] = off;
      int c = ctl->counts[e];
      int nt = (c + 127) >> 7;
      for (int i = 0; i < nt; i++) {
        if (t < MAXT)
          ctl->tileMap[t] = make_int4(e, off + i * 128, min(128, c - i * 128), 0);
        t++;
      }
      off += c;
    }
    ctl->totalTiles = t;
    for (; t < MAXT; t++) ctl->tileMap[t] = make_int4(0, 0, 0, 0);
  }
}

// ---------------- scatter: token -> gathered row ----------------
__global__ void k_scatter(Ctl* __restrict__ ctl) {
  int tok = blockIdx.x * blockDim.x + threadIdx.x;
  if (tok >= MTOK) return;
#pragma unroll
  for (int k = 0; k < 2; k++) {
    int e = ctl->topE[tok][k];
    int p = atomicAdd(&ctl->cursor[e], 1);
    ctl->rowTok[p] = tok;
    ctl->pos[tok][k] = p;
  }
}

// ---------------- GEMM1: h = silu(x@w1[e]) * (x@w3[e]), gathered rows ----------------
// block 512 thr = 8 waves (2x4), tile 128(M) x 128(N), BK=32, K=HD
__launch_bounds__(512, 1)
__global__ void k_gemm1(const float* __restrict__ x, const float* __restrict__ w1,
                        const float* __restrict__ w3, unsigned short* __restrict__ hg,
                        const Ctl* __restrict__ ctl) {
  __shared__ __align__(16) unsigned short ldsA[128 * 40];
  __shared__ __align__(16) unsigned short ldsB1[128 * 40];
  __shared__ __align__(16) unsigned short ldsB3[128 * 40];
  int rt = blockIdx.x % MAXT;
  int ct = blockIdx.x / MAXT;
  int4 tm = ctl->tileMap[rt];
  if (tm.z == 0) return;
  int e = tm.x, grow0 = tm.y, nrows = tm.z;
  int tid = threadIdx.x;

  int arow = tid >> 2, aslot = tid & 3;
  const float* aSrc = nullptr;
  if (arow < nrows) {
    int tokn = ctl->rowTok[grow0 + arow];
    aSrc = x + (size_t)tokn * HD + aslot * 8;
  }
  int bn = tid & 127, bk = tid >> 7;
  int ncol = ct * 128 + bn;
  const float* b1Src = w1 + ((size_t)e * HD + bk * 8) * FD + ncol;
  const float* b3Src = w3 + ((size_t)e * HD + bk * 8) * FD + ncol;

  int lane = tid & 63, wv = tid >> 6;
  int wr = wv >> 2, wc = wv & 3;
  int aOff = (wr * 64 + (lane & 15)) * 40 + (lane >> 4) * 8;
  int bOff = (wc * 32 + (lane & 15)) * 40 + (lane >> 4) * 8;

  f32x4 accA[4][2] = {};
  f32x4 accC[4][2] = {};

  for (int kt = 0; kt < HD / 32; kt++) {
    uint4 ap = make_uint4(0u, 0u, 0u, 0u);
    if (aSrc) {
      float4 f0 = *(const float4*)(aSrc + kt * 32);
      float4 f1 = *(const float4*)(aSrc + kt * 32 + 4);
      ap = make_uint4(pk2(f0.x, f0.y), pk2(f0.z, f0.w), pk2(f1.x, f1.y), pk2(f1.z, f1.w));
    }
    float bv1[8], bv3[8];
    const float* p1 = b1Src + (size_t)kt * 32 * FD;
    const float* p3 = b3Src + (size_t)kt * 32 * FD;
#pragma unroll
    for (int i = 0; i < 8; i++) { bv1[i] = p1[(size_t)i * FD]; bv3[i] = p3[(size_t)i * FD]; }
    uint4 bp1 = make_uint4(pk2(bv1[0], bv1[1]), pk2(bv1[2], bv1[3]), pk2(bv1[4], bv1[5]), pk2(bv1[6], bv1[7]));
    uint4 bp3 = make_uint4(pk2(bv3[0], bv3[1]), pk2(bv3[2], bv3[3]), pk2(bv3[4], bv3[5]), pk2(bv3[6], bv3[7]));
    __syncthreads();
    *(uint4*)&ldsA[arow * 40 + aslot * 8] = ap;
    *(uint4*)&ldsB1[bn * 40 + bk * 8] = bp1;
    *(uint4*)&ldsB3[bn * 40 + bk * 8] = bp3;
    __syncthreads();
    bf16x8 af[4];
#pragma unroll
    for (int ma = 0; ma < 4; ma++) af[ma] = *(const bf16x8*)&ldsA[aOff + ma * 16 * 40];
#pragma unroll
    for (int nb = 0; nb < 2; nb++) {
      bf16x8 bf1 = *(const bf16x8*)&ldsB1[bOff + nb * 16 * 40];
      bf16x8 bf3 = *(const bf16x8*)&ldsB3[bOff + nb * 16 * 40];
#pragma unroll
      for (int ma = 0; ma < 4; ma++) {
        accA[ma][nb] = __builtin_amdgcn_mfma_f32_16x16x32_bf16(af[ma], bf1, accA[ma][nb], 0, 0, 0);
        accC[ma][nb] = __builtin_amdgcn_mfma_f32_16x16x32_bf16(af[ma], bf3, accC[ma][nb], 0, 0, 0);
      }
    }
  }
#pragma unroll
  for (int ma = 0; ma < 4; ma++) {
    int lrowBase = wr * 64 + ma * 16 + (lane >> 4) * 4;
#pragma unroll
    for (int nb = 0; nb < 2; nb++) {
      int col = ct * 128 + wc * 32 + nb * 16 + (lane & 15);
#pragma unroll
      for (int r = 0; r < 4; r++) {
        int lrow = lrowBase + r;
        if (lrow < nrows) {
          float a = accA[ma][nb][r];
          float c = accC[ma][nb][r];
          float hv = a / (1.f + __expf(-a)) * c;   // silu(a)*c
          hg[(size_t)(grow0 + lrow) * FD + col] = f2bf(hv);
        }
      }
    }
  }
}

// ---------------- GEMM2: og = h @ w2[e], gathered rows ----------------
__launch_bounds__(512, 1)
__global__ void k_gemm2(const unsigned short* __restrict__ hg, const float* __restrict__ w2,
                        unsigned short* __restrict__ og, const Ctl* __restrict__ ctl) {
  __shared__ __align__(16) unsigned short ldsA[128 * 40];
  __shared__ __align__(16) unsigned short ldsB[128 * 40];
  int rt = blockIdx.x % MAXT;
  int ct = blockIdx.x / MAXT;
  int4 tm = ctl->tileMap[rt];
  if (tm.z == 0) return;
  int e = tm.x, grow0 = tm.y, nrows = tm.z;
  int tid = threadIdx.x;

  int arow = tid >> 2, aslot = tid & 3;
  const unsigned short* aSrc = nullptr;
  if (arow < nrows) aSrc = hg + (size_t)(grow0 + arow) * FD + aslot * 8;
  int bn = tid & 127, bk = tid >> 7;
  int ncol = ct * 128 + bn;
  const float* bSrc = w2 + ((size_t)e * FD + bk * 8) * HD + ncol;

  int lane = tid & 63, wv = tid >> 6;
  int wr = wv >> 2, wc = wv & 3;
  int aOff = (wr * 64 + (lane & 15)) * 40 + (lane >> 4) * 8;
  int bOff = (wc * 32 + (lane & 15)) * 40 + (lane >> 4) * 8;

  f32x4 acc[4][2] = {};

  for (int kt = 0; kt < FD / 32; kt++) {
    uint4 ap = make_uint4(0u, 0u, 0u, 0u);
    if (aSrc) ap = *(const uint4*)(aSrc + kt * 32);
    float bv[8];
    const float* p = bSrc + (size_t)kt * 32 * HD;
#pragma unroll
    for (int i = 0; i < 8; i++) bv[i] = p[(size_t)i * HD];
    uint4 bp = make_uint4(pk2(bv[0], bv[1]), pk2(bv[2], bv[3]), pk2(bv[4], bv[5]), pk2(bv[6], bv[7]));
    __syncthreads();
    *(uint4*)&ldsA[arow * 40 + aslot * 8] = ap;
    *(uint4*)&ldsB[bn * 40 + bk * 8] = bp;
    __syncthreads();
    bf16x8 af[4];
#pragma unroll
    for (int ma = 0; ma < 4; ma++) af[ma] = *(const bf16x8*)&ldsA[aOff + ma * 16 * 40];
#pragma unroll
    for (int nb = 0; nb < 2; nb++) {
      bf16x8 bfr = *(const bf16x8*)&ldsB[bOff + nb * 16 * 40];
#pragma unroll
      for (int ma = 0; ma < 4; ma++)
        acc[ma][nb] = __builtin_amdgcn_mfma_f32_16x16x32_bf16(af[ma], bfr, acc[ma][nb], 0, 0, 0);
    }
  }
#pragma unroll
  for (int ma = 0; ma < 4; ma++) {
    int lrowBase = wr * 64 + ma * 16 + (lane >> 4) * 4;
#pragma unroll
    for (int nb = 0; nb < 2; nb++) {
      int col = ct * 128 + wc * 32 + nb * 16 + (lane & 15);
#pragma unroll
      for (int r = 0; r < 4; r++) {
        int lrow = lrowBase + r;
        if (lrow < nrows)
          og[(size_t)(grow0 + lrow) * HD + col] = f2bf(acc[ma][nb][r]);
      }
    }
  }
}

// ---------------- combine: out[t] = w0*og[pos0] + w1*og[pos1] ----------------
__global__ void k_combine(const unsigned short* __restrict__ og, float* __restrict__ out,
                          const Ctl* __restrict__ ctl) {
  int tok = blockIdx.x;
  int tid = threadIdx.x;
  int p0 = ctl->pos[tok][0], p1 = ctl->pos[tok][1];
  float w0 = ctl->topW[tok][0], w1 = ctl->topW[tok][1];
  uint2 a = *(const uint2*)(og + (size_t)p0 * HD + tid * 4);
  uint2 b = *(const uint2*)(og + (size_t)p1 * HD + tid * 4);
  float4 o;
  o.x = w0 * bf2f((unsigned short)(a.x & 0xffffu)) + w1 * bf2f((unsigned short)(b.x & 0xffffu));
  o.y = w0 * bf2f((unsigned short)(a.x >> 16))     + w1 * bf2f((unsigned short)(b.x >> 16));
  o.z = w0 * bf2f((unsigned short)(a.y & 0xffffu)) + w1 * bf2f((unsigned short)(b.y & 0xffffu));
  o.w = w0 * bf2f((unsigned short)(a.y >> 16))     + w1 * bf2f((unsigned short)(b.y >> 16));
  *(float4*)(out + (size_t)tok * HD + tid * 4) = o;
}

extern "C" void kernel_launch(void* const* d_in, const int* in_sizes, int n_in,
                              void* d_out, int out_size, void* d_ws, size_t ws_size,
                              hipStream_t stream) {
  const float* x  = (const float*)d_in[0];   // [4,1024,1024]
  const float* gw = (const float*)d_in[1];   // [1024,8]
  const float* w1 = (const float*)d_in[2];   // [8,1024,2048]
  const float* w2 = (const float*)d_in[3];   // [8,2048,1024]
  const float* w3 = (const float*)d_in[4];   // [8,1024,2048]
  float* out = (float*)d_out;

  char* ws = (char*)d_ws;
  unsigned short* hg = (unsigned short*)ws;                               // 8192x2048 bf16 = 32 MiB
  unsigned short* og = (unsigned short*)(ws + (size_t)2 * MTOK * FD * 2); // 8192x1024 bf16 = 16 MiB
  Ctl* ctl = (Ctl*)(ws + (size_t)2 * MTOK * FD * 2 + (size_t)2 * MTOK * HD * 2);

  hipMemsetAsync(ctl->counts, 0, sizeof(int) * NEXP, stream);
  k_router<<<dim3(MTOK / 4), 256, 0, stream>>>(x, gw, ctl);
  k_setup<<<1, 64, 0, stream>>>(ctl);
  k_scatter<<<dim3(MTOK / 256), 256, 0, stream>>>(ctl);
  k_gemm1<<<dim3(MAXT * (FD / 128)), 512, 0, stream>>>(x, w1, w3, hg, ctl);
  k_gemm2<<<dim3(MAXT * (HD / 128)), 512, 0, stream>>>(hg, w2, og, ctl);
  k_combine<<<dim3(MTOK), 256, 0, stream>>>(og, out, ctl);
}

// Round 2
// 512.609 us; speedup vs baseline: 1.2722x; 1.2722x over previous
//
#include <hip/hip_runtime.h>

typedef __attribute__((ext_vector_type(8))) short bf16x8;
typedef __attribute__((ext_vector_type(4))) float f32x4;

#define MTOK 4096
#define HD 1024
#define FD 2048
#define NEXP 8
#define MAXT 72   // >= sum ceil(cnt_e/128) <= 63+8

struct Ctl {
  int counts[NEXP];
  int cursor[NEXP];
  int totalTiles;
  int _pad[7];
  int4 tileMap[MAXT];        // {expert, growStart, rowsValid, 0}
  int topE[MTOK][2];
  float topW[MTOK][2];
  int pos[MTOK][2];
  int rowTok[2 * MTOK];
};

__device__ __forceinline__ unsigned short f2bf(float f) {
  unsigned int u = __float_as_uint(f);
  unsigned int r = u + 0x7fffu + ((u >> 16) & 1u);   // RNE
  return (unsigned short)(r >> 16);
}
__device__ __forceinline__ float bf2f(unsigned short s) {
  return __uint_as_float(((unsigned int)s) << 16);
}
__device__ __forceinline__ unsigned int pk2(float a, float b) {
  return (unsigned int)f2bf(a) | ((unsigned int)f2bf(b) << 16);
}
// async global->LDS, 16B per lane; LDS dest must be linear (wave base + lane*16)
__device__ __forceinline__ void gload16(const void* g, void* l) {
  __builtin_amdgcn_global_load_lds(
      (const __attribute__((address_space(1))) void*)g,
      (__attribute__((address_space(3))) void*)l, 16, 0, 0);
}

// ---------------- transpose + bf16 convert: in [E][K][N] f32 -> out [E][N][K] bf16 ----------
__global__ void k_tr(const float* __restrict__ in, unsigned short* __restrict__ outp,
                     int K, int N) {
  __shared__ float tile[64][65];
  int ntn = N >> 6, ntk = K >> 6;
  int bid = blockIdx.x;
  int e = bid / (ntk * ntn);
  int rem = bid % (ntk * ntn);
  int kt = rem / ntn, nt = rem % ntn;
  const float* src = in + (size_t)e * K * N + (size_t)(kt * 64) * N + nt * 64;
  unsigned short* dst = outp + (size_t)e * N * K + (size_t)(nt * 64) * K + kt * 64;
  int t = threadIdx.x;
  int nl = t & 63, kq = t >> 6;
#pragma unroll
  for (int i = 0; i < 16; i++) {
    int kl = kq * 16 + i;
    tile[kl][nl] = src[(size_t)kl * N + nl];
  }
  __syncthreads();
  int n2 = t >> 2, kc = (t & 3) * 16;
  unsigned int pk[8];
#pragma unroll
  for (int j = 0; j < 8; j++)
    pk[j] = pk2(tile[kc + 2 * j][n2], tile[kc + 2 * j + 1][n2]);
  *(uint4*)(dst + (size_t)n2 * K + kc) = make_uint4(pk[0], pk[1], pk[2], pk[3]);
  *(uint4*)(dst + (size_t)n2 * K + kc + 8) = make_uint4(pk[4], pk[5], pk[6], pk[7]);
}

// ---------------- x f32 -> bf16 ----------------
__global__ void k_cvt_x(const float* __restrict__ x, unsigned short* __restrict__ xb) {
  int i = blockIdx.x * 256 + threadIdx.x;          // 8 elems per thread
  const float4* s = (const float4*)x;
  float4 a = s[i * 2], b = s[i * 2 + 1];
  *(uint4*)(xb + (size_t)i * 8) =
      make_uint4(pk2(a.x, a.y), pk2(a.z, a.w), pk2(b.x, b.y), pk2(b.z, b.w));
}

// ---------------- router ----------------
__global__ void k_router(const float* __restrict__ x, const float* __restrict__ gw,
                         Ctl* __restrict__ ctl) {
  int gt = blockIdx.x * blockDim.x + threadIdx.x;
  int tok = gt >> 6;
  int lane = gt & 63;
  if (tok >= MTOK) return;
  const float* xr = x + (size_t)tok * HD;
  float acc[NEXP];
#pragma unroll
  for (int e = 0; e < NEXP; e++) acc[e] = 0.f;
  for (int h = lane; h < HD; h += 64) {
    float xv = xr[h];
    float4 g0 = *(const float4*)(gw + h * NEXP);
    float4 g1 = *(const float4*)(gw + h * NEXP + 4);
    acc[0] += xv * g0.x; acc[1] += xv * g0.y; acc[2] += xv * g0.z; acc[3] += xv * g0.w;
    acc[4] += xv * g1.x; acc[5] += xv * g1.y; acc[6] += xv * g1.z; acc[7] += xv * g1.w;
  }
#pragma unroll
  for (int off = 32; off > 0; off >>= 1) {
#pragma unroll
    for (int e = 0; e < NEXP; e++) acc[e] += __shfl_xor(acc[e], off);
  }
  if (lane == 0) {
    float l0 = -1e30f, l1 = -1e30f; int i0 = 0, i1 = 0;
#pragma unroll
    for (int e = 0; e < NEXP; e++) {
      float v = acc[e];
      if (v > l0) { l1 = l0; i1 = i0; l0 = v; i0 = e; }
      else if (v > l1) { l1 = v; i1 = e; }
    }
    float w0 = 1.f / (1.f + __expf(l1 - l0));
    ctl->topE[tok][0] = i0; ctl->topE[tok][1] = i1;
    ctl->topW[tok][0] = w0; ctl->topW[tok][1] = 1.f - w0;
    atomicAdd(&ctl->counts[i0], 1);
    atomicAdd(&ctl->counts[i1], 1);
  }
}

__global__ void k_setup(Ctl* __restrict__ ctl) {
  if (threadIdx.x == 0 && blockIdx.x == 0) {
    int off = 0, t = 0;
    for (int e = 0; e < NEXP; e++) {
      ctl->cursor[e] = off;
      int c = ctl->counts[e];
      int nt = (c + 127) >> 7;
      for (int i = 0; i < nt; i++) {
        if (t < MAXT)
          ctl->tileMap[t] = make_int4(e, off + i * 128, min(128, c - i * 128), 0);
        t++;
      }
      off += c;
    }
    ctl->totalTiles = t;
    for (; t < MAXT; t++) ctl->tileMap[t] = make_int4(0, 0, 0, 0);
  }
}

__global__ void k_scatter(Ctl* __restrict__ ctl) {
  int tok = blockIdx.x * blockDim.x + threadIdx.x;
  if (tok >= MTOK) return;
#pragma unroll
  for (int k = 0; k < 2; k++) {
    int e = ctl->topE[tok][k];
    int p = atomicAdd(&ctl->cursor[e], 1);
    ctl->rowTok[p] = tok;
    ctl->pos[tok][k] = p;
  }
}

// ======== GEMM1: h = silu(x@w1[e]) * (x@w3[e]); A,B1,B3 staged via global_load_lds ========
// tile 128x128, BK=32, 512 thr (8 waves 2x4), double-buffered, counted vmcnt
__launch_bounds__(512, 2)
__global__ void k_gemm1(const unsigned short* __restrict__ xb,
                        const unsigned short* __restrict__ w1t,
                        const unsigned short* __restrict__ w3t,
                        unsigned short* __restrict__ hg,
                        const Ctl* __restrict__ ctl) {
  __shared__ __align__(1024) unsigned char lds[2][3][8192];
  int nwg = MAXT * (FD / 128);
  int bid = blockIdx.x;
  int swz = (bid & 7) * (nwg >> 3) + (bid >> 3);   // bijective XCD swizzle (nwg%8==0)
  int rt = swz % MAXT, ct = swz / MAXT;
  int4 tm = ctl->tileMap[rt];
  if (tm.z == 0) return;
  int e = tm.x, grow0 = tm.y, nrows = tm.z;
  int t = threadIdx.x;

  // staging: thread t -> LDS slot (row=t>>2, chunk=t&3); source chunk XOR-swizzled
  int r = t >> 2;
  int cl = (t & 3) ^ ((r >> 1) & 3);
  int rA = min(r, nrows - 1);
  int tok = ctl->rowTok[grow0 + rA];
  const unsigned short* aG  = xb  + (size_t)tok * HD + cl * 8;
  const unsigned short* b1G = w1t + ((size_t)e * FD + ct * 128 + r) * HD + cl * 8;
  const unsigned short* b3G = w3t + ((size_t)e * FD + ct * 128 + r) * HD + cl * 8;
  unsigned char* ldsDstA  = &lds[0][0][t * 16];
  unsigned char* ldsDstB1 = &lds[0][1][t * 16];
  unsigned char* ldsDstB3 = &lds[0][2][t * 16];

  int lane = t & 63, wv = t >> 6, wr = wv >> 2, wc = wv & 3;
  int lm = lane & 15, lk = lane >> 4;
  int aOff[4], bOff[2];
#pragma unroll
  for (int ma = 0; ma < 4; ma++) {
    int row = wr * 64 + ma * 16 + lm;
    aOff[ma] = row * 64 + ((lk ^ ((row >> 1) & 3)) << 4);
  }
#pragma unroll
  for (int nb = 0; nb < 2; nb++) {
    int row = wc * 32 + nb * 16 + lm;
    bOff[nb] = row * 64 + ((lk ^ ((row >> 1) & 3)) << 4);
  }

  f32x4 accA[4][2] = {};
  f32x4 accC[4][2] = {};

  const int NK = HD / 32;
  // prologue: stage tile 0 into buf 0
  gload16(aG, ldsDstA); gload16(b1G, ldsDstB1); gload16(b3G, ldsDstB3);
  for (int kt = 0; kt < NK; kt++) {
    int b = kt & 1;
    if (kt + 1 < NK) {
      size_t ko = (size_t)(kt + 1) * 32;
      int nbuf = b ^ 1;
      gload16(aG + ko,  ldsDstA  + nbuf * 3 * 8192);
      gload16(b1G + ko, ldsDstB1 + nbuf * 3 * 8192);
      gload16(b3G + ko, ldsDstB3 + nbuf * 3 * 8192);
      asm volatile("s_waitcnt vmcnt(3)" ::: "memory");   // cur tile landed; next 3 in flight
    } else {
      asm volatile("s_waitcnt vmcnt(0)" ::: "memory");
    }
    __builtin_amdgcn_s_barrier();
    asm volatile("" ::: "memory");
    const unsigned char* pA  = &lds[b][0][0];
    const unsigned char* pB1 = &lds[b][1][0];
    const unsigned char* pB3 = &lds[b][2][0];
    bf16x8 af[4], bf1[2], bf3[2];
#pragma unroll
    for (int ma = 0; ma < 4; ma++) af[ma] = *(const bf16x8*)(pA + aOff[ma]);
#pragma unroll
    for (int nb = 0; nb < 2; nb++) {
      bf1[nb] = *(const bf16x8*)(pB1 + bOff[nb]);
      bf3[nb] = *(const bf16x8*)(pB3 + bOff[nb]);
    }
#pragma unroll
    for (int nb = 0; nb < 2; nb++)
#pragma unroll
      for (int ma = 0; ma < 4; ma++) {
        accA[ma][nb] = __builtin_amdgcn_mfma_f32_16x16x32_bf16(af[ma], bf1[nb], accA[ma][nb], 0, 0, 0);
        accC[ma][nb] = __builtin_amdgcn_mfma_f32_16x16x32_bf16(af[ma], bf3[nb], accC[ma][nb], 0, 0, 0);
      }
    asm volatile("" ::: "memory");
    __builtin_amdgcn_s_barrier();   // all waves done reading buf b before it's restaged
  }

#pragma unroll
  for (int ma = 0; ma < 4; ma++) {
    int lrowBase = wr * 64 + ma * 16 + lk * 4;
#pragma unroll
    for (int nb = 0; nb < 2; nb++) {
      int col = ct * 128 + wc * 32 + nb * 16 + lm;
#pragma unroll
      for (int rr = 0; rr < 4; rr++) {
        int lrow = lrowBase + rr;
        if (lrow < nrows) {
          float a = accA[ma][nb][rr];
          float c = accC[ma][nb][rr];
          float hv = a / (1.f + __expf(-a)) * c;   // silu(a)*c
          hg[(size_t)(grow0 + lrow) * FD + col] = f2bf(hv);
        }
      }
    }
  }
}

// ======== GEMM2: og = h @ w2t[e]; same structure, 2 staged tiles ========
__launch_bounds__(512, 2)
__global__ void k_gemm2(const unsigned short* __restrict__ hg,
                        const unsigned short* __restrict__ w2t,
                        unsigned short* __restrict__ og,
                        const Ctl* __restrict__ ctl) {
  __shared__ __align__(1024) unsigned char lds[2][2][8192];
  int nwg = MAXT * (HD / 128);
  int bid = blockIdx.x;
  int swz = (bid & 7) * (nwg >> 3) + (bid >> 3);
  int rt = swz % MAXT, ct = swz / MAXT;
  int4 tm = ctl->tileMap[rt];
  if (tm.z == 0) return;
  int e = tm.x, grow0 = tm.y, nrows = tm.z;
  int t = threadIdx.x;

  int r = t >> 2;
  int cl = (t & 3) ^ ((r >> 1) & 3);
  int rA = min(r, nrows - 1);
  const unsigned short* aG = hg  + (size_t)(grow0 + rA) * FD + cl * 8;
  const unsigned short* bG = w2t + ((size_t)e * HD + ct * 128 + r) * FD + cl * 8;
  unsigned char* ldsDstA = &lds[0][0][t * 16];
  unsigned char* ldsDstB = &lds[0][1][t * 16];

  int lane = t & 63, wv = t >> 6, wr = wv >> 2, wc = wv & 3;
  int lm = lane & 15, lk = lane >> 4;
  int aOff[4], bOff[2];
#pragma unroll
  for (int ma = 0; ma < 4; ma++) {
    int row = wr * 64 + ma * 16 + lm;
    aOff[ma] = row * 64 + ((lk ^ ((row >> 1) & 3)) << 4);
  }
#pragma unroll
  for (int nb = 0; nb < 2; nb++) {
    int row = wc * 32 + nb * 16 + lm;
    bOff[nb] = row * 64 + ((lk ^ ((row >> 1) & 3)) << 4);
  }

  f32x4 acc[4][2] = {};
  const int NK = FD / 32;
  gload16(aG, ldsDstA); gload16(bG, ldsDstB);
  for (int kt = 0; kt < NK; kt++) {
    int b = kt & 1;
    if (kt + 1 < NK) {
      size_t ko = (size_t)(kt + 1) * 32;
      int nbuf = b ^ 1;
      gload16(aG + ko, ldsDstA + nbuf * 2 * 8192);
      gload16(bG + ko, ldsDstB + nbuf * 2 * 8192);
      asm volatile("s_waitcnt vmcnt(2)" ::: "memory");
    } else {
      asm volatile("s_waitcnt vmcnt(0)" ::: "memory");
    }
    __builtin_amdgcn_s_barrier();
    asm volatile("" ::: "memory");
    const unsigned char* pA = &lds[b][0][0];
    const unsigned char* pB = &lds[b][1][0];
    bf16x8 af[4], bfr[2];
#pragma unroll
    for (int ma = 0; ma < 4; ma++) af[ma] = *(const bf16x8*)(pA + aOff[ma]);
#pragma unroll
    for (int nb = 0; nb < 2; nb++) bfr[nb] = *(const bf16x8*)(pB + bOff[nb]);
#pragma unroll
    for (int nb = 0; nb < 2; nb++)
#pragma unroll
      for (int ma = 0; ma < 4; ma++)
        acc[ma][nb] = __builtin_amdgcn_mfma_f32_16x16x32_bf16(af[ma], bfr[nb], acc[ma][nb], 0, 0, 0);
    asm volatile("" ::: "memory");
    __builtin_amdgcn_s_barrier();
  }

#pragma unroll
  for (int ma = 0; ma < 4; ma++) {
    int lrowBase = wr * 64 + ma * 16 + lk * 4;
#pragma unroll
    for (int nb = 0; nb < 2; nb++) {
      int col = ct * 128 + wc * 32 + nb * 16 + lm;
#pragma unroll
      for (int rr = 0; rr < 4; rr++) {
        int lrow = lrowBase + rr;
        if (lrow < nrows)
          og[(size_t)(grow0 + lrow) * HD + col] = f2bf(acc[ma][nb][rr]);
      }
    }
  }
}

// ---------------- combine ----------------
__global__ void k_combine(const unsigned short* __restrict__ og, float* __restrict__ out,
                          const Ctl* __restrict__ ctl) {
  int tok = blockIdx.x;
  int tid = threadIdx.x;
  int p0 = ctl->pos[tok][0], p1 = ctl->pos[tok][1];
  float w0 = ctl->topW[tok][0], w1 = ctl->topW[tok][1];
  uint2 a = *(const uint2*)(og + (size_t)p0 * HD + tid * 4);
  uint2 b = *(const uint2*)(og + (size_t)p1 * HD + tid * 4);
  float4 o;
  o.x = w0 * bf2f((unsigned short)(a.x & 0xffffu)) + w1 * bf2f((unsigned short)(b.x & 0xffffu));
  o.y = w0 * bf2f((unsigned short)(a.x >> 16))     + w1 * bf2f((unsigned short)(b.x >> 16));
  o.z = w0 * bf2f((unsigned short)(a.y & 0xffffu)) + w1 * bf2f((unsigned short)(b.y & 0xffffu));
  o.w = w0 * bf2f((unsigned short)(a.y >> 16))     + w1 * bf2f((unsigned short)(b.y >> 16));
  *(float4*)(out + (size_t)tok * HD + tid * 4) = o;
}

extern "C" void kernel_launch(void* const* d_in, const int* in_sizes, int n_in,
                              void* d_out, int out_size, void* d_ws, size_t ws_size,
                              hipStream_t stream) {
  const float* x  = (const float*)d_in[0];   // [4,1024,1024]
  const float* gw = (const float*)d_in[1];   // [1024,8]
  const float* w1 = (const float*)d_in[2];   // [8,1024,2048]
  const float* w2 = (const float*)d_in[3];   // [8,2048,1024]
  const float* w3 = (const float*)d_in[4];   // [8,1024,2048]
  float* out = (float*)d_out;

  char* ws = (char*)d_ws;
  unsigned short* hg  = (unsigned short*)(ws);                         // 32 MB
  unsigned short* og  = (unsigned short*)(ws + (size_t)(32u << 20));   // 16 MB
  unsigned short* xb  = (unsigned short*)(ws + (size_t)(48u << 20));   // 8 MB
  unsigned short* wAt = (unsigned short*)(ws + (size_t)(56u << 20));   // 32 MB (w1t, then w2t)
  unsigned short* wBt = (unsigned short*)(ws + (size_t)(88u << 20));   // 32 MB (w3t)
  Ctl* ctl = (Ctl*)(ws + (size_t)(120u << 20));

  hipMemsetAsync(ctl->counts, 0, sizeof(int) * NEXP, stream);
  k_tr<<<dim3(8 * 16 * 32), 256, 0, stream>>>(w1, wAt, HD, FD);
  k_tr<<<dim3(8 * 16 * 32), 256, 0, stream>>>(w3, wBt, HD, FD);
  k_cvt_x<<<dim3(2048), 256, 0, stream>>>(x, xb);
  k_router<<<dim3(MTOK / 4), 256, 0, stream>>>(x, gw, ctl);
  k_setup<<<1, 64, 0, stream>>>(ctl);
  k_scatter<<<dim3(MTOK / 256), 256, 0, stream>>>(ctl);
  k_gemm1<<<dim3(MAXT * (FD / 128)), 512, 0, stream>>>(xb, wAt, wBt, hg, ctl);
  k_tr<<<dim3(8 * 32 * 16), 256, 0, stream>>>(w2, wAt, FD, HD);   // w2t reuses w1t space
  k_gemm2<<<dim3(MAXT * (HD / 128)), 512, 0, stream>>>(hg, wAt, og, ctl);
  k_combine<<<dim3(MTOK), 256, 0, stream>>>(og, out, ctl);
}

// Round 3
// 400.604 us; speedup vs baseline: 1.6279x; 1.2796x over previous
//
#include <hip/hip_runtime.h>

typedef __attribute__((ext_vector_type(8))) short bf16x8;
typedef __attribute__((ext_vector_type(4))) float f32x4;

#define MTOK 4096
#define HD 1024
#define FD 2048
#define NEXP 8
#define MAXT 72   // >= sum ceil(cnt_e/128) <= 63+8

struct Ctl {
  int counts[NEXP];
  int cursor[NEXP];
  int totalTiles;
  int _pad[7];
  int4 tileMap[MAXT];        // {expert, growStart, rowsValid, 0}
  int topE[MTOK][2];
  float topW[MTOK][2];
  int pos[MTOK][2];
  int rowTok[2 * MTOK];
};

__device__ __forceinline__ unsigned short f2bf(float f) {
  unsigned int u = __float_as_uint(f);
  unsigned int r = u + 0x7fffu + ((u >> 16) & 1u);   // RNE
  return (unsigned short)(r >> 16);
}
__device__ __forceinline__ float bf2f(unsigned short s) {
  return __uint_as_float(((unsigned int)s) << 16);
}
__device__ __forceinline__ unsigned int pk2(float a, float b) {
  return (unsigned int)f2bf(a) | ((unsigned int)f2bf(b) << 16);
}
// async global->LDS, 16B per lane; LDS dest must be linear (wave base + lane*16)
__device__ __forceinline__ void gload16(const void* g, void* l) {
  __builtin_amdgcn_global_load_lds(
      (const __attribute__((address_space(1))) void*)g,
      (__attribute__((address_space(3))) void*)l, 16, 0, 0);
}

// ---------------- transpose + bf16 convert: in [E][K][N] f32 -> out [E][N][K] bf16 ----------
__global__ void k_tr(const float* __restrict__ in, unsigned short* __restrict__ outp,
                     int K, int N) {
  __shared__ float tile[64][65];
  int ntn = N >> 6, ntk = K >> 6;
  int bid = blockIdx.x;
  int e = bid / (ntk * ntn);
  int rem = bid % (ntk * ntn);
  int kt = rem / ntn, nt = rem % ntn;
  const float* src = in + (size_t)e * K * N + (size_t)(kt * 64) * N + nt * 64;
  unsigned short* dst = outp + (size_t)e * N * K + (size_t)(nt * 64) * K + kt * 64;
  int t = threadIdx.x;
  int nl = t & 63, kq = t >> 6;
#pragma unroll
  for (int i = 0; i < 16; i++) {
    int kl = kq * 16 + i;
    tile[kl][nl] = src[(size_t)kl * N + nl];
  }
  __syncthreads();
  int n2 = t >> 2, kc = (t & 3) * 16;
  unsigned int pk[8];
#pragma unroll
  for (int j = 0; j < 8; j++)
    pk[j] = pk2(tile[kc + 2 * j][n2], tile[kc + 2 * j + 1][n2]);
  *(uint4*)(dst + (size_t)n2 * K + kc) = make_uint4(pk[0], pk[1], pk[2], pk[3]);
  *(uint4*)(dst + (size_t)n2 * K + kc + 8) = make_uint4(pk[4], pk[5], pk[6], pk[7]);
}

// ---------------- x f32 -> bf16 ----------------
__global__ void k_cvt_x(const float* __restrict__ x, unsigned short* __restrict__ xb) {
  int i = blockIdx.x * 256 + threadIdx.x;          // 8 elems per thread
  const float4* s = (const float4*)x;
  float4 a = s[i * 2], b = s[i * 2 + 1];
  *(uint4*)(xb + (size_t)i * 8) =
      make_uint4(pk2(a.x, a.y), pk2(a.z, a.w), pk2(b.x, b.y), pk2(b.z, b.w));
}

// ---------------- router: GEMV + top2, NO global atomics ----------------
__global__ void k_router(const float* __restrict__ x, const float* __restrict__ gw,
                         Ctl* __restrict__ ctl) {
  int gt = blockIdx.x * 256 + threadIdx.x;
  int tok = gt >> 6;
  int lane = gt & 63;
  const float* xr = x + (size_t)tok * HD;
  float acc[NEXP] = {};
#pragma unroll
  for (int it = 0; it < 4; it++) {
    int h0 = it * 256 + lane * 4;
    float4 xv = *(const float4*)(xr + h0);
    float xs[4] = {xv.x, xv.y, xv.z, xv.w};
#pragma unroll
    for (int j = 0; j < 4; j++) {
      float4 g0 = *(const float4*)(gw + (size_t)(h0 + j) * 8);
      float4 g1 = *(const float4*)(gw + (size_t)(h0 + j) * 8 + 4);
      acc[0] += xs[j] * g0.x; acc[1] += xs[j] * g0.y;
      acc[2] += xs[j] * g0.z; acc[3] += xs[j] * g0.w;
      acc[4] += xs[j] * g1.x; acc[5] += xs[j] * g1.y;
      acc[6] += xs[j] * g1.z; acc[7] += xs[j] * g1.w;
    }
  }
#pragma unroll
  for (int off = 32; off > 0; off >>= 1) {
#pragma unroll
    for (int e = 0; e < NEXP; e++) acc[e] += __shfl_xor(acc[e], off);
  }
  if (lane == 0) {
    float l0 = -1e30f, l1 = -1e30f; int i0 = 0, i1 = 0;
#pragma unroll
    for (int e = 0; e < NEXP; e++) {
      float v = acc[e];
      if (v > l0) { l1 = l0; i1 = i0; l0 = v; i0 = e; }
      else if (v > l1) { l1 = v; i1 = e; }
    }
    float w0 = 1.f / (1.f + __expf(l1 - l0));
    ctl->topE[tok][0] = i0; ctl->topE[tok][1] = i1;
    ctl->topW[tok][0] = w0; ctl->topW[tok][1] = 1.f - w0;
  }
}

// ---------------- count: LDS-hierarchical (64 global atomics total) ----------------
__global__ void k_count(Ctl* __restrict__ ctl) {
  __shared__ int lcnt[NEXP];
  int t = threadIdx.x;
  if (t < NEXP) lcnt[t] = 0;
  __syncthreads();
  int tok = blockIdx.x * 512 + t;
  atomicAdd(&lcnt[ctl->topE[tok][0]], 1);
  atomicAdd(&lcnt[ctl->topE[tok][1]], 1);
  __syncthreads();
  if (t < NEXP && lcnt[t]) atomicAdd(&ctl->counts[t], lcnt[t]);
}

// ---------------- prefix sums + tile map ----------------
__global__ void k_setup(Ctl* __restrict__ ctl) {
  if (threadIdx.x == 0 && blockIdx.x == 0) {
    int off = 0, t = 0;
    for (int e = 0; e < NEXP; e++) {
      ctl->cursor[e] = off;
      int c = ctl->counts[e];
      int nt = (c + 127) >> 7;
      for (int i = 0; i < nt; i++) {
        if (t < MAXT)
          ctl->tileMap[t] = make_int4(e, off + i * 128, min(128, c - i * 128), 0);
        t++;
      }
      off += c;
    }
    ctl->totalTiles = t;
    for (; t < MAXT; t++) ctl->tileMap[t] = make_int4(0, 0, 0, 0);
  }
}

// ---------------- scatter: LDS rank + one range-reserve atomic per expert per block ----------
__global__ void k_scatter(Ctl* __restrict__ ctl) {
  __shared__ int lcur[NEXP];
  __shared__ int gbase[NEXP];
  int t = threadIdx.x;
  int tok = blockIdx.x * 512 + t;
  if (t < NEXP) lcur[t] = 0;
  __syncthreads();
  int e0 = ctl->topE[tok][0];
  int e1 = ctl->topE[tok][1];
  int r0 = atomicAdd(&lcur[e0], 1);
  int r1 = atomicAdd(&lcur[e1], 1);
  __syncthreads();
  if (t < NEXP) gbase[t] = lcur[t] ? atomicAdd(&ctl->cursor[t], lcur[t]) : 0;
  __syncthreads();
  int p0 = gbase[e0] + r0;
  int p1 = gbase[e1] + r1;
  ctl->rowTok[p0] = tok; ctl->pos[tok][0] = p0;
  ctl->rowTok[p1] = tok; ctl->pos[tok][1] = p1;
}

// ======== GEMM1: h = silu(x@w1[e]) * (x@w3[e]); A,B1,B3 staged via global_load_lds ========
// tile 128x128, BK=32, 512 thr (8 waves 2x4), double-buffered, counted vmcnt
__launch_bounds__(512, 2)
__global__ void k_gemm1(const unsigned short* __restrict__ xb,
                        const unsigned short* __restrict__ w1t,
                        const unsigned short* __restrict__ w3t,
                        unsigned short* __restrict__ hg,
                        const Ctl* __restrict__ ctl) {
  __shared__ __align__(1024) unsigned char lds[2][3][8192];
  int nwg = MAXT * (FD / 128);
  int bid = blockIdx.x;
  int swz = (bid & 7) * (nwg >> 3) + (bid >> 3);   // bijective XCD swizzle (nwg%8==0)
  int rt = swz % MAXT, ct = swz / MAXT;
  int4 tm = ctl->tileMap[rt];
  if (tm.z == 0) return;
  int e = tm.x, grow0 = tm.y, nrows = tm.z;
  int t = threadIdx.x;

  // staging: thread t -> LDS slot (row=t>>2, chunk=t&3); source chunk XOR-swizzled
  int r = t >> 2;
  int cl = (t & 3) ^ ((r >> 1) & 3);
  int rA = min(r, nrows - 1);
  int tok = ctl->rowTok[grow0 + rA];
  const unsigned short* aG  = xb  + (size_t)tok * HD + cl * 8;
  const unsigned short* b1G = w1t + ((size_t)e * FD + ct * 128 + r) * HD + cl * 8;
  const unsigned short* b3G = w3t + ((size_t)e * FD + ct * 128 + r) * HD + cl * 8;
  unsigned char* ldsDstA  = &lds[0][0][t * 16];
  unsigned char* ldsDstB1 = &lds[0][1][t * 16];
  unsigned char* ldsDstB3 = &lds[0][2][t * 16];

  int lane = t & 63, wv = t >> 6, wr = wv >> 2, wc = wv & 3;
  int lm = lane & 15, lk = lane >> 4;
  int aOff[4], bOff[2];
#pragma unroll
  for (int ma = 0; ma < 4; ma++) {
    int row = wr * 64 + ma * 16 + lm;
    aOff[ma] = row * 64 + ((lk ^ ((row >> 1) & 3)) << 4);
  }
#pragma unroll
  for (int nb = 0; nb < 2; nb++) {
    int row = wc * 32 + nb * 16 + lm;
    bOff[nb] = row * 64 + ((lk ^ ((row >> 1) & 3)) << 4);
  }

  f32x4 accA[4][2] = {};
  f32x4 accC[4][2] = {};

  const int NK = HD / 32;
  gload16(aG, ldsDstA); gload16(b1G, ldsDstB1); gload16(b3G, ldsDstB3);
  for (int kt = 0; kt < NK; kt++) {
    int b = kt & 1;
    if (kt + 1 < NK) {
      size_t ko = (size_t)(kt + 1) * 32;
      int nbuf = b ^ 1;
      gload16(aG + ko,  ldsDstA  + nbuf * 3 * 8192);
      gload16(b1G + ko, ldsDstB1 + nbuf * 3 * 8192);
      gload16(b3G + ko, ldsDstB3 + nbuf * 3 * 8192);
      asm volatile("s_waitcnt vmcnt(3)" ::: "memory");   // cur tile landed; next 3 in flight
    } else {
      asm volatile("s_waitcnt vmcnt(0)" ::: "memory");
    }
    __builtin_amdgcn_s_barrier();
    asm volatile("" ::: "memory");
    const unsigned char* pA  = &lds[b][0][0];
    const unsigned char* pB1 = &lds[b][1][0];
    const unsigned char* pB3 = &lds[b][2][0];
    bf16x8 af[4], bf1[2], bf3[2];
#pragma unroll
    for (int ma = 0; ma < 4; ma++) af[ma] = *(const bf16x8*)(pA + aOff[ma]);
#pragma unroll
    for (int nb = 0; nb < 2; nb++) {
      bf1[nb] = *(const bf16x8*)(pB1 + bOff[nb]);
      bf3[nb] = *(const bf16x8*)(pB3 + bOff[nb]);
    }
#pragma unroll
    for (int nb = 0; nb < 2; nb++)
#pragma unroll
      for (int ma = 0; ma < 4; ma++) {
        accA[ma][nb] = __builtin_amdgcn_mfma_f32_16x16x32_bf16(af[ma], bf1[nb], accA[ma][nb], 0, 0, 0);
        accC[ma][nb] = __builtin_amdgcn_mfma_f32_16x16x32_bf16(af[ma], bf3[nb], accC[ma][nb], 0, 0, 0);
      }
    asm volatile("" ::: "memory");
    __builtin_amdgcn_s_barrier();   // all waves done reading buf b before it's restaged
  }

#pragma unroll
  for (int ma = 0; ma < 4; ma++) {
    int lrowBase = wr * 64 + ma * 16 + lk * 4;
#pragma unroll
    for (int nb = 0; nb < 2; nb++) {
      int col = ct * 128 + wc * 32 + nb * 16 + lm;
#pragma unroll
      for (int rr = 0; rr < 4; rr++) {
        int lrow = lrowBase + rr;
        if (lrow < nrows) {
          float a = accA[ma][nb][rr];
          float c = accC[ma][nb][rr];
          float hv = a / (1.f + __expf(-a)) * c;   // silu(a)*c
          hg[(size_t)(grow0 + lrow) * FD + col] = f2bf(hv);
        }
      }
    }
  }
}

// ======== GEMM2: og = h @ w2t[e]; same structure, 2 staged tiles ========
__launch_bounds__(512, 2)
__global__ void k_gemm2(const unsigned short* __restrict__ hg,
                        const unsigned short* __restrict__ w2t,
                        unsigned short* __restrict__ og,
                        const Ctl* __restrict__ ctl) {
  __shared__ __align__(1024) unsigned char lds[2][2][8192];
  int nwg = MAXT * (HD / 128);
  int bid = blockIdx.x;
  int swz = (bid & 7) * (nwg >> 3) + (bid >> 3);
  int rt = swz % MAXT, ct = swz / MAXT;
  int4 tm = ctl->tileMap[rt];
  if (tm.z == 0) return;
  int e = tm.x, grow0 = tm.y, nrows = tm.z;
  int t = threadIdx.x;

  int r = t >> 2;
  int cl = (t & 3) ^ ((r >> 1) & 3);
  int rA = min(r, nrows - 1);
  const unsigned short* aG = hg  + (size_t)(grow0 + rA) * FD + cl * 8;
  const unsigned short* bG = w2t + ((size_t)e * HD + ct * 128 + r) * FD + cl * 8;
  unsigned char* ldsDstA = &lds[0][0][t * 16];
  unsigned char* ldsDstB = &lds[0][1][t * 16];

  int lane = t & 63, wv = t >> 6, wr = wv >> 2, wc = wv & 3;
  int lm = lane & 15, lk = lane >> 4;
  int aOff[4], bOff[2];
#pragma unroll
  for (int ma = 0; ma < 4; ma++) {
    int row = wr * 64 + ma * 16 + lm;
    aOff[ma] = row * 64 + ((lk ^ ((row >> 1) & 3)) << 4);
  }
#pragma unroll
  for (int nb = 0; nb < 2; nb++) {
    int row = wc * 32 + nb * 16 + lm;
    bOff[nb] = row * 64 + ((lk ^ ((row >> 1) & 3)) << 4);
  }

  f32x4 acc[4][2] = {};
  const int NK = FD / 32;
  gload16(aG, ldsDstA); gload16(bG, ldsDstB);
  for (int kt = 0; kt < NK; kt++) {
    int b = kt & 1;
    if (kt + 1 < NK) {
      size_t ko = (size_t)(kt + 1) * 32;
      int nbuf = b ^ 1;
      gload16(aG + ko, ldsDstA + nbuf * 2 * 8192);
      gload16(bG + ko, ldsDstB + nbuf * 2 * 8192);
      asm volatile("s_waitcnt vmcnt(2)" ::: "memory");
    } else {
      asm volatile("s_waitcnt vmcnt(0)" ::: "memory");
    }
    __builtin_amdgcn_s_barrier();
    asm volatile("" ::: "memory");
    const unsigned char* pA = &lds[b][0][0];
    const unsigned char* pB = &lds[b][1][0];
    bf16x8 af[4], bfr[2];
#pragma unroll
    for (int ma = 0; ma < 4; ma++) af[ma] = *(const bf16x8*)(pA + aOff[ma]);
#pragma unroll
    for (int nb = 0; nb < 2; nb++) bfr[nb] = *(const bf16x8*)(pB + bOff[nb]);
#pragma unroll
    for (int nb = 0; nb < 2; nb++)
#pragma unroll
      for (int ma = 0; ma < 4; ma++)
        acc[ma][nb] = __builtin_amdgcn_mfma_f32_16x16x32_bf16(af[ma], bfr[nb], acc[ma][nb], 0, 0, 0);
    asm volatile("" ::: "memory");
    __builtin_amdgcn_s_barrier();
  }

#pragma unroll
  for (int ma = 0; ma < 4; ma++) {
    int lrowBase = wr * 64 + ma * 16 + lk * 4;
#pragma unroll
    for (int nb = 0; nb < 2; nb++) {
      int col = ct * 128 + wc * 32 + nb * 16 + lm;
#pragma unroll
      for (int rr = 0; rr < 4; rr++) {
        int lrow = lrowBase + rr;
        if (lrow < nrows)
          og[(size_t)(grow0 + lrow) * HD + col] = f2bf(acc[ma][nb][rr]);
      }
    }
  }
}

// ---------------- combine ----------------
__global__ void k_combine(const unsigned short* __restrict__ og, float* __restrict__ out,
                          const Ctl* __restrict__ ctl) {
  int tok = blockIdx.x;
  int tid = threadIdx.x;
  int p0 = ctl->pos[tok][0], p1 = ctl->pos[tok][1];
  float w0 = ctl->topW[tok][0], w1 = ctl->topW[tok][1];
  uint2 a = *(const uint2*)(og + (size_t)p0 * HD + tid * 4);
  uint2 b = *(const uint2*)(og + (size_t)p1 * HD + tid * 4);
  float4 o;
  o.x = w0 * bf2f((unsigned short)(a.x & 0xffffu)) + w1 * bf2f((unsigned short)(b.x & 0xffffu));
  o.y = w0 * bf2f((unsigned short)(a.x >> 16))     + w1 * bf2f((unsigned short)(b.x >> 16));
  o.z = w0 * bf2f((unsigned short)(a.y & 0xffffu)) + w1 * bf2f((unsigned short)(b.y & 0xffffu));
  o.w = w0 * bf2f((unsigned short)(a.y >> 16))     + w1 * bf2f((unsigned short)(b.y >> 16));
  *(float4*)(out + (size_t)tok * HD + tid * 4) = o;
}

extern "C" void kernel_launch(void* const* d_in, const int* in_sizes, int n_in,
                              void* d_out, int out_size, void* d_ws, size_t ws_size,
                              hipStream_t stream) {
  const float* x  = (const float*)d_in[0];   // [4,1024,1024]
  const float* gw = (const float*)d_in[1];   // [1024,8]
  const float* w1 = (const float*)d_in[2];   // [8,1024,2048]
  const float* w2 = (const float*)d_in[3];   // [8,2048,1024]
  const float* w3 = (const float*)d_in[4];   // [8,1024,2048]
  float* out = (float*)d_out;

  char* ws = (char*)d_ws;
  unsigned short* hg  = (unsigned short*)(ws);                         // 32 MB
  unsigned short* og  = (unsigned short*)(ws + (size_t)(32u << 20));   // 16 MB
  unsigned short* xb  = (unsigned short*)(ws + (size_t)(48u << 20));   // 8 MB
  unsigned short* wAt = (unsigned short*)(ws + (size_t)(56u << 20));   // 32 MB (w1t, then w2t)
  unsigned short* wBt = (unsigned short*)(ws + (size_t)(88u << 20));   // 32 MB (w3t)
  Ctl* ctl = (Ctl*)(ws + (size_t)(120u << 20));

  hipMemsetAsync(ctl->counts, 0, sizeof(int) * NEXP, stream);
  k_tr<<<dim3(8 * 16 * 32), 256, 0, stream>>>(w1, wAt, HD, FD);
  k_tr<<<dim3(8 * 16 * 32), 256, 0, stream>>>(w3, wBt, HD, FD);
  k_cvt_x<<<dim3(2048), 256, 0, stream>>>(x, xb);
  k_router<<<dim3(MTOK / 4), 256, 0, stream>>>(x, gw, ctl);
  k_count<<<dim3(MTOK / 512), 512, 0, stream>>>(ctl);
  k_setup<<<1, 64, 0, stream>>>(ctl);
  k_scatter<<<dim3(MTOK / 512), 512, 0, stream>>>(ctl);
  k_gemm1<<<dim3(MAXT * (FD / 128)), 512, 0, stream>>>(xb, wAt, wBt, hg, ctl);
  k_tr<<<dim3(8 * 32 * 16), 256, 0, stream>>>(w2, wAt, FD, HD);   // w2t reuses w1t space
  k_gemm2<<<dim3(MAXT * (HD / 128)), 512, 0, stream>>>(hg, wAt, og, ctl);
  k_combine<<<dim3(MTOK), 256, 0, stream>>>(og, out, ctl);
}